// Round 1
// baseline (2765.947 us; speedup 1.0000x reference)
//
#include <hip/hip_runtime.h>
#include <hip/hip_bf16.h>
#include <math.h>

#define B_ 4
#define N_ 4096
#define D_ 768
#define KTOP 8
#define M_ (B_*N_)          // 16384
#define SSPLIT 4            // K-range splits in sim kernel

// ---------------------------------------------------------------------------
// Kernel 1: fused QKV GEMM.  C[M,2304] = feats[M,768] @ [Wq|Wkv] + [bq|bkv]
// scattered into Q, K, V ([M,768] each). 128x128 tile, 8x8 micro, BK=8.
// ---------------------------------------------------------------------------
#define G1_BM 128
#define G1_BN 128
#define G1_BK 8

__global__ __launch_bounds__(256) void qkv_gemm(
    const float* __restrict__ feats, const float* __restrict__ Wq,
    const float* __restrict__ bq,    const float* __restrict__ Wkv,
    const float* __restrict__ bkv,   float* __restrict__ Q,
    float* __restrict__ Km,          float* __restrict__ Vm)
{
    __shared__ float As[G1_BK][G1_BM];
    __shared__ float Bs[G1_BK][G1_BN];

    const int tid = threadIdx.x;
    const int n0  = blockIdx.x * G1_BN;   // 0..2303 (multiple of 128)
    const int m0  = blockIdx.y * G1_BM;
    const int tx  = tid & 15, ty = tid >> 4;

    // column tile lies entirely within Wq or Wkv (768 % 128 == 0)
    const float* Wsrc; int wld, wcol0;
    if (n0 < 768) { Wsrc = Wq;  wld = 768;  wcol0 = n0; }
    else          { Wsrc = Wkv; wld = 1536; wcol0 = n0 - 768; }

    const int ar = tid >> 1;           // 0..127
    const int ak = (tid & 1) * 4;      // 0 or 4
    const int br = tid >> 5;           // 0..7
    const int bc = (tid & 31) * 4;     // 0..124

    float acc[8][8];
#pragma unroll
    for (int i = 0; i < 8; ++i)
#pragma unroll
        for (int j = 0; j < 8; ++j) acc[i][j] = 0.f;

    for (int kb = 0; kb < D_ / G1_BK; ++kb) {
        const float4 av = *(const float4*)&feats[(size_t)(m0 + ar) * D_ + kb * G1_BK + ak];
        const float4 bv = *(const float4*)&Wsrc[(size_t)(kb * G1_BK + br) * wld + wcol0 + bc];
        As[ak + 0][ar] = av.x; As[ak + 1][ar] = av.y;
        As[ak + 2][ar] = av.z; As[ak + 3][ar] = av.w;
        *(float4*)&Bs[br][bc] = bv;
        __syncthreads();
#pragma unroll
        for (int k = 0; k < G1_BK; ++k) {
            float a[8], b[8];
            *(float4*)&a[0] = *(const float4*)&As[k][ty * 8];
            *(float4*)&a[4] = *(const float4*)&As[k][ty * 8 + 4];
            *(float4*)&b[0] = *(const float4*)&Bs[k][tx * 8];
            *(float4*)&b[4] = *(const float4*)&Bs[k][tx * 8 + 4];
#pragma unroll
            for (int i = 0; i < 8; ++i)
#pragma unroll
                for (int j = 0; j < 8; ++j) acc[i][j] += a[i] * b[j];
        }
        __syncthreads();
    }

    // epilogue: bias + scatter to Q/K/V
    const float* bsrc = (n0 < 768) ? (bq + n0) : (bkv + (n0 - 768));
    float bias[8];
#pragma unroll
    for (int j = 0; j < 8; ++j) bias[j] = bsrc[tx * 8 + j];

    float* dst; int dcol0;
    if      (n0 < 768)  { dst = Q;  dcol0 = n0; }
    else if (n0 < 1536) { dst = Km; dcol0 = n0 - 768; }
    else                { dst = Vm; dcol0 = n0 - 1536; }

#pragma unroll
    for (int i = 0; i < 8; ++i) {
        const int row = m0 + ty * 8 + i;
        float4 o0, o1;
        o0.x = acc[i][0] + bias[0]; o0.y = acc[i][1] + bias[1];
        o0.z = acc[i][2] + bias[2]; o0.w = acc[i][3] + bias[3];
        o1.x = acc[i][4] + bias[4]; o1.y = acc[i][5] + bias[5];
        o1.z = acc[i][6] + bias[6]; o1.w = acc[i][7] + bias[7];
        *(float4*)&dst[(size_t)row * D_ + dcol0 + tx * 8]     = o0;
        *(float4*)&dst[(size_t)row * D_ + dcol0 + tx * 8 + 4] = o1;
    }
}

// ---------------------------------------------------------------------------
// Kernel 2: reciprocal row L2 norms of Q and K. One wave per row.
// ---------------------------------------------------------------------------
__global__ __launch_bounds__(256) void rownorms(
    const float* __restrict__ Q, const float* __restrict__ Km,
    float* __restrict__ rqinv, float* __restrict__ rkinv)
{
    const int wave = blockIdx.x * 4 + (threadIdx.x >> 6);
    const int lane = threadIdx.x & 63;
    const float* src; float* dstv; int r;
    if (wave < M_) { src = Q;  dstv = rqinv; r = wave; }
    else           { src = Km; dstv = rkinv; r = wave - M_; }
    const float* p = src + (size_t)r * D_ + lane * 12;
    float s = 0.f;
#pragma unroll
    for (int i = 0; i < 3; ++i) {
        const float4 v = *(const float4*)&p[i * 4];
        s += v.x * v.x + v.y * v.y + v.z * v.z + v.w * v.w;
    }
#pragma unroll
    for (int off = 32; off; off >>= 1) s += __shfl_xor(s, off);
    if (lane == 0) dstv[r] = 1.0f / fmaxf(sqrtf(s), 1e-12f);
}

// ---------------------------------------------------------------------------
// Kernel 3: cosine-sim GEMM with fused streaming top-8 (diagonal excluded).
// Each block: 64 Q-rows x a 1024-wide K-range (split 4-way), chunked by 64.
// Owners (tid<64) keep a sorted top-8 in registers (static-index network).
// ---------------------------------------------------------------------------
#define T3M 64
#define T3N 64
#define T3K 16

__global__ __launch_bounds__(256) void sim_topk(
    const float* __restrict__ Q, const float* __restrict__ Kmat,
    const float* __restrict__ rqinv, const float* __restrict__ rkinv,
    float* __restrict__ simPart, int* __restrict__ idxPart)
{
    __shared__ float As[T3K][T3M];
    __shared__ float Bs[T3K][T3N];
    __shared__ float St[T3M][T3N + 1];

    const int tid = threadIdx.x;
    const int qt = blockIdx.x;          // 0..63
    const int ks = blockIdx.y;          // 0..3
    const int b  = blockIdx.z;          // 0..3
    const float* Qb = Q    + (size_t)b * N_ * D_;
    const float* Kb = Kmat + (size_t)b * N_ * D_;
    const int qrow0 = qt * T3M;
    const int tx = tid & 15, ty = tid >> 4;

    float bsim[KTOP]; int bidx[KTOP];
#pragma unroll
    for (int i = 0; i < KTOP; ++i) { bsim[i] = -1e30f; bidx[i] = 0x7fffffff; }

    float rqv[4];
#pragma unroll
    for (int i = 0; i < 4; ++i) rqv[i] = rqinv[(size_t)b * N_ + qrow0 + ty * 4 + i];

    const int lr = tid >> 2;          // 0..63
    const int lk = (tid & 3) * 4;     // 0,4,8,12

    for (int c = 0; c < 1024 / T3N; ++c) {
        const int kcol0 = ks * 1024 + c * T3N;
        float acc[4][4];
#pragma unroll
        for (int i = 0; i < 4; ++i)
#pragma unroll
            for (int j = 0; j < 4; ++j) acc[i][j] = 0.f;

        for (int kb = 0; kb < D_ / T3K; ++kb) {
            const float4 av = *(const float4*)&Qb[(size_t)(qrow0 + lr) * D_ + kb * T3K + lk];
            const float4 bv = *(const float4*)&Kb[(size_t)(kcol0 + lr) * D_ + kb * T3K + lk];
            As[lk + 0][lr] = av.x; As[lk + 1][lr] = av.y;
            As[lk + 2][lr] = av.z; As[lk + 3][lr] = av.w;
            Bs[lk + 0][lr] = bv.x; Bs[lk + 1][lr] = bv.y;
            Bs[lk + 2][lr] = bv.z; Bs[lk + 3][lr] = bv.w;
            __syncthreads();
#pragma unroll
            for (int k = 0; k < T3K; ++k) {
                float a[4], bb[4];
                *(float4*)a  = *(const float4*)&As[k][ty * 4];
                *(float4*)bb = *(const float4*)&Bs[k][tx * 4];
#pragma unroll
                for (int i = 0; i < 4; ++i)
#pragma unroll
                    for (int j = 0; j < 4; ++j) acc[i][j] += a[i] * bb[j];
            }
            __syncthreads();
        }

        // scaled sim tile -> LDS
        float rkv[4];
#pragma unroll
        for (int j = 0; j < 4; ++j) rkv[j] = rkinv[(size_t)b * N_ + kcol0 + tx * 4 + j];
#pragma unroll
        for (int i = 0; i < 4; ++i)
#pragma unroll
            for (int j = 0; j < 4; ++j)
                St[ty * 4 + i][tx * 4 + j] = acc[i][j] * rqv[i] * rkv[j];
        __syncthreads();

        // owner scan: one thread per Q-row
        if (tid < T3M) {
            const int qglob = qrow0 + tid;
            for (int j = 0; j < T3N; ++j) {
                const int kg = kcol0 + j;
                const float s = St[tid][j];
                if (kg == qglob) continue;   // self excluded (+1e6 on diagonal)
                if (s > bsim[KTOP - 1] ||
                    (s == bsim[KTOP - 1] && kg < bidx[KTOP - 1])) {
                    // unrolled static-index insertion into sorted-desc list
#pragma unroll
                    for (int i = KTOP - 1; i >= 1; --i) {
                        const bool bi   = (s > bsim[i])     || (s == bsim[i]     && kg < bidx[i]);
                        const bool bim1 = (s > bsim[i - 1]) || (s == bsim[i - 1] && kg < bidx[i - 1]);
                        const float ns = bim1 ? bsim[i - 1] : s;
                        const int   ni = bim1 ? bidx[i - 1] : kg;
                        bsim[i] = bi ? ns : bsim[i];
                        bidx[i] = bi ? ni : bidx[i];
                    }
                    const bool b0 = (s > bsim[0]) || (s == bsim[0] && kg < bidx[0]);
                    if (b0) { bsim[0] = s; bidx[0] = kg; }
                }
            }
        }
        __syncthreads();
    }

    if (tid < T3M) {
        const size_t base = ((((size_t)b * SSPLIT + ks) * N_) + qrow0 + tid) * KTOP;
#pragma unroll
        for (int i = 0; i < KTOP; ++i) { simPart[base + i] = bsim[i]; idxPart[base + i] = bidx[i]; }
    }
}

// ---------------------------------------------------------------------------
// Kernel 4: zero output
// ---------------------------------------------------------------------------
__global__ void zero_out(float* __restrict__ out)
{
    const int i = blockIdx.x * 256 + threadIdx.x;
    if (i < B_ * D_) out[i] = 0.f;
}

// ---------------------------------------------------------------------------
// Kernel 5: merge 4 partial top-8s (rank select), 8-neighbor attention,
// accumulate batch mean. One wave per row, 16 rows per block.
// ---------------------------------------------------------------------------
__global__ __launch_bounds__(256) void merge_attn(
    const float* __restrict__ Q, const float* __restrict__ Kmat,
    const float* __restrict__ Vmat, const float* __restrict__ simPart,
    const int* __restrict__ idxPart, float* __restrict__ out)
{
    __shared__ float laccum[4][D_];
    const int tid  = threadIdx.x;
    const int w    = tid >> 6, lane = tid & 63;
    const int r0   = blockIdx.x * 16;          // 16 rows per block, same batch
    const int b    = r0 / N_;
    const float scale = 1.0f / 27.712812921102035f;   // 1/sqrt(768)

    float oacc[12];
#pragma unroll
    for (int i = 0; i < 12; ++i) oacc[i] = 0.f;

    for (int rr = 0; rr < 4; ++rr) {
        const int row = r0 + w * 4 + rr;       // global row
        const int n   = row - b * N_;

        // ---- merge 4x8 partial candidates via rank selection ----
        float cs; int ci;
        if (lane < 32) {
            const int sp = lane >> 3, slot = lane & 7;
            const size_t base = ((((size_t)b * SSPLIT + sp) * N_) + n) * KTOP + slot;
            cs = simPart[base]; ci = idxPart[base];
        } else { cs = -1e38f; ci = 0x7fffffff; }
        int rank = 0;
#pragma unroll
        for (int o = 0; o < 32; ++o) {
            const float os = __shfl(cs, o);
            const int   oi = __shfl(ci, o);
            rank += ((os > cs) || (os == cs && oi < ci)) ? 1 : 0;
        }
        unsigned long long win = __ballot(lane < 32 && rank < KTOP);
        int nj[KTOP];
#pragma unroll
        for (int j = 0; j < KTOP; ++j) {
            const int src = __ffsll((unsigned long long)win) - 1;
            win &= win - 1;
            nj[j] = __shfl(ci, src);
        }

        // ---- attention scores: a_j = (Q_row . K_nj) / sqrt(D) ----
        float qv[12];
        {
            const float* qp = Q + (size_t)row * D_ + lane * 12;
#pragma unroll
            for (int i = 0; i < 3; ++i) *(float4*)&qv[i * 4] = *(const float4*)&qp[i * 4];
        }
        float a[KTOP];
#pragma unroll
        for (int j = 0; j < KTOP; ++j) {
            const float* kp = Kmat + ((size_t)b * N_ + nj[j]) * D_ + lane * 12;
            float d = 0.f;
#pragma unroll
            for (int i = 0; i < 3; ++i) {
                const float4 kv = *(const float4*)&kp[i * 4];
                d += qv[i * 4 + 0] * kv.x + qv[i * 4 + 1] * kv.y +
                     qv[i * 4 + 2] * kv.z + qv[i * 4 + 3] * kv.w;
            }
#pragma unroll
            for (int off = 32; off; off >>= 1) d += __shfl_xor(d, off);
            a[j] = d * scale;
        }

        // ---- softmax over 8 ----
        float m = a[0];
#pragma unroll
        for (int j = 1; j < KTOP; ++j) m = fmaxf(m, a[j]);
        float e[KTOP]; float ssum = 0.f;
#pragma unroll
        for (int j = 0; j < KTOP; ++j) { e[j] = expf(a[j] - m); ssum += e[j]; }
        const float inv = 1.0f / ssum;

        // ---- weighted V sum ----
#pragma unroll
        for (int j = 0; j < KTOP; ++j) {
            const float p = e[j] * inv;
            const float* vp = Vmat + ((size_t)b * N_ + nj[j]) * D_ + lane * 12;
#pragma unroll
            for (int i = 0; i < 3; ++i) {
                const float4 vv = *(const float4*)&vp[i * 4];
                oacc[i * 4 + 0] += p * vv.x; oacc[i * 4 + 1] += p * vv.y;
                oacc[i * 4 + 2] += p * vv.z; oacc[i * 4 + 3] += p * vv.w;
            }
        }
    }

    // wave-level accumulators -> LDS -> one atomicAdd per element per block
#pragma unroll
    for (int i = 0; i < 3; ++i)
        *(float4*)&laccum[w][lane * 12 + i * 4] = *(float4*)&oacc[i * 4];
    __syncthreads();
    for (int d = tid; d < D_; d += 256) {
        const float s = laccum[0][d] + laccum[1][d] + laccum[2][d] + laccum[3][d];
        atomicAdd(&out[(size_t)b * D_ + d], s * (1.0f / N_));
    }
}

// ---------------------------------------------------------------------------
extern "C" void kernel_launch(void* const* d_in, const int* in_sizes, int n_in,
                              void* d_out, int out_size, void* d_ws, size_t ws_size,
                              hipStream_t stream)
{
    const float* feats = (const float*)d_in[0];
    const float* Wq    = (const float*)d_in[1];
    const float* bq    = (const float*)d_in[2];
    const float* Wkv   = (const float*)d_in[3];
    const float* bkv   = (const float*)d_in[4];
    float* out = (float*)d_out;

    // workspace layout (~148 MB)
    char* ws = (char*)d_ws;
    size_t off = 0;
    float* Q  = (float*)(ws + off); off += (size_t)M_ * D_ * sizeof(float);
    float* Km = (float*)(ws + off); off += (size_t)M_ * D_ * sizeof(float);
    float* Vm = (float*)(ws + off); off += (size_t)M_ * D_ * sizeof(float);
    float* rqinv = (float*)(ws + off); off += (size_t)M_ * sizeof(float);
    float* rkinv = (float*)(ws + off); off += (size_t)M_ * sizeof(float);
    float* simPart = (float*)(ws + off); off += (size_t)B_ * SSPLIT * N_ * KTOP * sizeof(float);
    int*   idxPart = (int*)(ws + off);   off += (size_t)B_ * SSPLIT * N_ * KTOP * sizeof(int);
    (void)ws_size; (void)in_sizes; (void)n_in; (void)out_size;

    qkv_gemm<<<dim3(2304 / G1_BN, M_ / G1_BM), 256, 0, stream>>>(
        feats, Wq, bq, Wkv, bkv, Q, Km, Vm);
    rownorms<<<(2 * M_) / 4, 256, 0, stream>>>(Q, Km, rqinv, rkinv);
    sim_topk<<<dim3(N_ / T3M, SSPLIT, B_), 256, 0, stream>>>(
        Q, Km, rqinv, rkinv, simPart, idxPart);
    zero_out<<<(B_ * D_ + 255) / 256, 256, 0, stream>>>(out);
    merge_attn<<<M_ / 16, 256, 0, stream>>>(Q, Km, Vm, simPart, idxPart, out);
}

// Round 3
// 1189.929 us; speedup vs baseline: 2.3245x; 2.3245x over previous
//
#include <hip/hip_runtime.h>
#include <hip/hip_bf16.h>
#include <math.h>

#define B_ 4
#define N_ 4096
#define D_ 768
#define KTOP 8
#define M_ (B_*N_)          // 16384
#define TCAND 12            // bf16 candidates kept per row (margin over KTOP=8)
#define KSPLIT 16           // k-range splits in select kernel (256 k each)

typedef __attribute__((ext_vector_type(8))) short short8;
typedef __attribute__((ext_vector_type(4))) float f32x4;

__device__ __forceinline__ ushort f2bf(float f) {
    unsigned int u = __float_as_uint(f);
    unsigned int r = (u + 0x7FFFu + ((u >> 16) & 1u)) >> 16;
    return (ushort)r;
}

__device__ __forceinline__ void gload16(const void* g, void* l) {
    __builtin_amdgcn_global_load_lds(
        (const __attribute__((address_space(1))) unsigned int*)g,
        (__attribute__((address_space(3))) unsigned int*)l, 16, 0, 0);
}

// ---------------------------------------------------------------------------
// Kernel 1: fused QKV GEMM (fp32).
// ---------------------------------------------------------------------------
#define G1_BM 128
#define G1_BN 128
#define G1_BK 8

__global__ __launch_bounds__(256) void qkv_gemm(
    const float* __restrict__ feats, const float* __restrict__ Wq,
    const float* __restrict__ bq,    const float* __restrict__ Wkv,
    const float* __restrict__ bkv,   float* __restrict__ Q,
    float* __restrict__ Km,          float* __restrict__ Vm)
{
    __shared__ float As[G1_BK][G1_BM];
    __shared__ float Bs[G1_BK][G1_BN];

    const int tid = threadIdx.x;
    const int n0  = blockIdx.x * G1_BN;
    const int m0  = blockIdx.y * G1_BM;
    const int tx  = tid & 15, ty = tid >> 4;

    const float* Wsrc; int wld, wcol0;
    if (n0 < 768) { Wsrc = Wq;  wld = 768;  wcol0 = n0; }
    else          { Wsrc = Wkv; wld = 1536; wcol0 = n0 - 768; }

    const int ar = tid >> 1;
    const int ak = (tid & 1) * 4;
    const int br = tid >> 5;
    const int bc = (tid & 31) * 4;

    float acc[8][8];
#pragma unroll
    for (int i = 0; i < 8; ++i)
#pragma unroll
        for (int j = 0; j < 8; ++j) acc[i][j] = 0.f;

    for (int kb = 0; kb < D_ / G1_BK; ++kb) {
        const float4 av = *(const float4*)&feats[(size_t)(m0 + ar) * D_ + kb * G1_BK + ak];
        const float4 bv = *(const float4*)&Wsrc[(size_t)(kb * G1_BK + br) * wld + wcol0 + bc];
        As[ak + 0][ar] = av.x; As[ak + 1][ar] = av.y;
        As[ak + 2][ar] = av.z; As[ak + 3][ar] = av.w;
        *(float4*)&Bs[br][bc] = bv;
        __syncthreads();
#pragma unroll
        for (int k = 0; k < G1_BK; ++k) {
            float a[8], b[8];
            *(float4*)&a[0] = *(const float4*)&As[k][ty * 8];
            *(float4*)&a[4] = *(const float4*)&As[k][ty * 8 + 4];
            *(float4*)&b[0] = *(const float4*)&Bs[k][tx * 8];
            *(float4*)&b[4] = *(const float4*)&Bs[k][tx * 8 + 4];
#pragma unroll
            for (int i = 0; i < 8; ++i)
#pragma unroll
                for (int j = 0; j < 8; ++j) acc[i][j] += a[i] * b[j];
        }
        __syncthreads();
    }

    const float* bsrc = (n0 < 768) ? (bq + n0) : (bkv + (n0 - 768));
    float bias[8];
#pragma unroll
    for (int j = 0; j < 8; ++j) bias[j] = bsrc[tx * 8 + j];

    float* dst; int dcol0;
    if      (n0 < 768)  { dst = Q;  dcol0 = n0; }
    else if (n0 < 1536) { dst = Km; dcol0 = n0 - 768; }
    else                { dst = Vm; dcol0 = n0 - 1536; }

#pragma unroll
    for (int i = 0; i < 8; ++i) {
        const int row = m0 + ty * 8 + i;
        float4 o0, o1;
        o0.x = acc[i][0] + bias[0]; o0.y = acc[i][1] + bias[1];
        o0.z = acc[i][2] + bias[2]; o0.w = acc[i][3] + bias[3];
        o1.x = acc[i][4] + bias[4]; o1.y = acc[i][5] + bias[5];
        o1.z = acc[i][6] + bias[6]; o1.w = acc[i][7] + bias[7];
        *(float4*)&dst[(size_t)row * D_ + dcol0 + tx * 8]     = o0;
        *(float4*)&dst[(size_t)row * D_ + dcol0 + tx * 8 + 4] = o1;
    }
}

// ---------------------------------------------------------------------------
// Kernel 2: row L2 norms of Q,K + write normalized bf16 copies + 1/norm.
// One wave per row.
// ---------------------------------------------------------------------------
__global__ __launch_bounds__(256) void norm_bf16(
    const float* __restrict__ Q, const float* __restrict__ Km,
    ushort* __restrict__ qn, ushort* __restrict__ kn,
    float* __restrict__ rqinv, float* __restrict__ rkinv)
{
    const int wid  = blockIdx.x * 4 + (threadIdx.x >> 6);
    const int lane = threadIdx.x & 63;
    const float* src; ushort* dst; float* rv; int r;
    if (wid < M_) { src = Q;  dst = qn; rv = rqinv; r = wid; }
    else          { src = Km; dst = kn; rv = rkinv; r = wid - M_; }
    const float* p = src + (size_t)r * D_ + lane * 12;
    float v[12];
#pragma unroll
    for (int i = 0; i < 3; ++i) *(float4*)&v[i * 4] = *(const float4*)&p[i * 4];
    float s = 0.f;
#pragma unroll
    for (int i = 0; i < 12; ++i) s += v[i] * v[i];
#pragma unroll
    for (int off = 32; off; off >>= 1) s += __shfl_xor(s, off);
    const float rinv = 1.0f / fmaxf(sqrtf(s), 1e-12f);
    ushort* op = dst + (size_t)r * D_ + lane * 12;
#pragma unroll
    for (int i = 0; i < 3; ++i) {
        ushort4 o;
        o.x = f2bf(v[i * 4 + 0] * rinv); o.y = f2bf(v[i * 4 + 1] * rinv);
        o.z = f2bf(v[i * 4 + 2] * rinv); o.w = f2bf(v[i * 4 + 3] * rinv);
        *(ushort4*)&op[i * 4] = o;
    }
    if (lane == 0) rv[r] = rinv;
}

// ---------------------------------------------------------------------------
// Kernel 3: bf16 MFMA sim GEMM (one batch): S[q][k] = qn . kn^T, bf16 out,
// diagonal forced to bf16 lowest. 128x128 tile, BK=64, 4 waves,
// global_load_lds width-16 staging (m97 structure).
// ---------------------------------------------------------------------------
__global__ __launch_bounds__(256) void sim_gemm(
    const ushort* __restrict__ qn, const ushort* __restrict__ kn,
    ushort* __restrict__ S)
{
    __shared__ __align__(16) ushort As[128 * 64];
    __shared__ __align__(16) ushort Bs[128 * 64];

    const int tid  = threadIdx.x;
    const int lane = tid & 63, w = tid >> 6;
    const int wr = w >> 1, wc = w & 1;
    const int r16 = lane & 15, kq = lane >> 4;
    const int k0 = blockIdx.x * 128;
    const int q0 = blockIdx.y * 128;

    const ushort* qsrc = qn + (size_t)(q0 + (tid >> 3)) * D_ + (tid & 7) * 8;
    const ushort* ksrc = kn + (size_t)(k0 + (tid >> 3)) * D_ + (tid & 7) * 8;
    ushort* lA = As + ((tid >> 6) << 9);   // wave-uniform: wave*512 ushorts
    ushort* lB = Bs + ((tid >> 6) << 9);

    f32x4 acc[4][4];
#pragma unroll
    for (int mi = 0; mi < 4; ++mi)
#pragma unroll
        for (int ni = 0; ni < 4; ++ni) acc[mi][ni] = (f32x4)0.f;

    for (int kb = 0; kb < D_ / 64; ++kb) {
#pragma unroll
        for (int i = 0; i < 4; ++i) {
            gload16(qsrc + (size_t)i * 32 * D_ + kb * 64, lA + i * 2048);
            gload16(ksrc + (size_t)i * 32 * D_ + kb * 64, lB + i * 2048);
        }
        __syncthreads();
#pragma unroll
        for (int kk = 0; kk < 2; ++kk) {
            short8 a[4], bfr[4];
#pragma unroll
            for (int mi = 0; mi < 4; ++mi)
                a[mi] = *(const short8*)&As[(wr * 64 + mi * 16 + r16) * 64 + kk * 32 + kq * 8];
#pragma unroll
            for (int ni = 0; ni < 4; ++ni)
                bfr[ni] = *(const short8*)&Bs[(wc * 64 + ni * 16 + r16) * 64 + kk * 32 + kq * 8];
#pragma unroll
            for (int mi = 0; mi < 4; ++mi)
#pragma unroll
                for (int ni = 0; ni < 4; ++ni)
                    acc[mi][ni] = __builtin_amdgcn_mfma_f32_16x16x32_bf16(
                        a[mi], bfr[ni], acc[mi][ni], 0, 0, 0);
        }
        __syncthreads();
    }

    // epilogue: C layout col=lane&15, row=(lane>>4)*4+reg
#pragma unroll
    for (int mi = 0; mi < 4; ++mi)
#pragma unroll
        for (int ni = 0; ni < 4; ++ni)
#pragma unroll
            for (int r = 0; r < 4; ++r) {
                const int qq = q0 + wr * 64 + mi * 16 + kq * 4 + r;
                const int kk = k0 + wc * 64 + ni * 16 + r16;
                const float val = acc[mi][ni][r];
                const ushort bv = (qq == kk) ? (ushort)0xFF7Fu : f2bf(val);
                S[(size_t)qq * N_ + kk] = bv;
            }
}

// ---------------------------------------------------------------------------
// Kernel 4: branchless packed top-12 per (row, 256-wide k split).
// lane = row; candidate packed as sortable(bf16)<<16 | (4095-k)
// (value desc, then lower k wins — matches stable top_k tie-break).
// ---------------------------------------------------------------------------
__global__ __launch_bounds__(256) void sel_topk(
    const ushort* __restrict__ S, unsigned int* __restrict__ Part)
{
    const int tid = threadIdx.x;
    const int row = blockIdx.x * 256 + tid;      // row within batch
    const int ks  = blockIdx.y;                  // 0..15
    const int kbase = ks * 256;
    const int KREV  = (N_ - 1) - kbase;

    const ushort* sp = S + (size_t)row * N_ + kbase;
    unsigned int t[TCAND];
#pragma unroll
    for (int i = 0; i < TCAND; ++i) t[i] = 0u;

    for (int j = 0; j < 256; j += 8) {
        const uint4 dv = *(const uint4*)(sp + j);
        unsigned int dw[4];
        dw[0] = dv.x; dw[1] = dv.y; dw[2] = dv.z; dw[3] = dv.w;
#pragma unroll
        for (int q = 0; q < 4; ++q) {
            const unsigned int vlo = dw[q] & 0xFFFFu;
            const unsigned int vhi = dw[q] >> 16;
            const unsigned int plo =
                ((vlo ^ (0x8000u + ((vlo >> 15) * 0x7FFFu))) << 16) |
                (unsigned int)(KREV - (j + 2 * q));
            const unsigned int phi =
                ((vhi ^ (0x8000u + ((vhi >> 15) * 0x7FFFu))) << 16) |
                (unsigned int)(KREV - (j + 2 * q + 1));
            unsigned int p = plo;
#pragma unroll
            for (int i = 0; i < TCAND; ++i) {
                const unsigned int mx = max(t[i], p);
                const unsigned int mn = min(t[i], p);
                t[i] = mx; p = mn;
            }
            p = phi;
#pragma unroll
            for (int i = 0; i < TCAND; ++i) {
                const unsigned int mx = max(t[i], p);
                const unsigned int mn = min(t[i], p);
                t[i] = mx; p = mn;
            }
        }
    }

    unsigned int* op = Part + (size_t)row * (KSPLIT * TCAND) + ks * TCAND;
#pragma unroll
    for (int i = 0; i < TCAND; ++i) op[i] = t[i];
}

// ---------------------------------------------------------------------------
// Kernel 5: zero output
// ---------------------------------------------------------------------------
__global__ void zero_out(float* __restrict__ out)
{
    const int i = blockIdx.x * 256 + threadIdx.x;
    if (i < B_ * D_) out[i] = 0.f;
}

// ---------------------------------------------------------------------------
// Kernel 6: merge 192 partials -> bf16 top-12 -> fp32 rescore (exact cos sim
// + attention logits) -> exact top-8 -> softmax -> V gather -> batch mean.
// One wave per row.
// ---------------------------------------------------------------------------
__global__ __launch_bounds__(256) void merge_rescore_attn(
    const float* __restrict__ Q, const float* __restrict__ Kmat,
    const float* __restrict__ Vmat, const float* __restrict__ rqinv,
    const float* __restrict__ rkinv, const unsigned int* __restrict__ Part,
    float* __restrict__ out)
{
    __shared__ float laccum[4][D_];
    const int tid  = threadIdx.x;
    const int w    = tid >> 6, lane = tid & 63;
    const int row  = blockIdx.x * 4 + w;         // global row
    const int b    = row >> 12;

    // ---- load 192 packed candidates, extract top-12 by 12x wave-argmax ----
    const unsigned int* pp = Part + (size_t)row * (KSPLIT * TCAND);
    unsigned int c0 = pp[lane], c1 = pp[64 + lane], c2 = pp[128 + lane];
    unsigned int mysel = 0u;
#pragma unroll
    for (int it = 0; it < TCAND; ++it) {
        unsigned int m = max(c0, max(c1, c2));
#pragma unroll
        for (int off = 32; off; off >>= 1) m = max(m, __shfl_xor(m, off));
        c0 = (c0 == m) ? 0u : c0;
        c1 = (c1 == m) ? 0u : c1;
        c2 = (c2 == m) ? 0u : c2;
        mysel = (lane == it) ? m : mysel;
    }
    const int kj_lane = (N_ - 1) - (int)(mysel & 0xFFFFu);

    // ---- fp32 rescore of the 12 candidates ----
    float qv[12];
    {
        const float* qp = Q + (size_t)row * D_ + lane * 12;
#pragma unroll
        for (int i = 0; i < 3; ++i) *(float4*)&qv[i * 4] = *(const float4*)&qp[i * 4];
    }
    const float rq = rqinv[row];
    const float scale = 0.03608439182435161f;   // 1/sqrt(768)

    float simv[TCAND], lgv[TCAND];
    int   ka[TCAND];
#pragma unroll
    for (int j = 0; j < TCAND; ++j) {
        const int kj = __shfl(kj_lane, j);
        ka[j] = kj;
        const float* kp = Kmat + ((size_t)(b << 12) + kj) * D_ + lane * 12;
        float d = 0.f;
#pragma unroll
        for (int i = 0; i < 3; ++i) {
            const float4 kv = *(const float4*)&kp[i * 4];
            d += qv[i * 4 + 0] * kv.x + qv[i * 4 + 1] * kv.y +
                 qv[i * 4 + 2] * kv.z + qv[i * 4 + 3] * kv.w;
        }
#pragma unroll
        for (int off = 32; off; off >>= 1) d += __shfl_xor(d, off);
        simv[j] = d * rq * rkinv[(b << 12) + kj];
        lgv[j]  = d * scale;
    }

    // ---- exact top-8 of 12 by (sim desc, idx asc) ----
    int rk8[TCAND];
#pragma unroll
    for (int j = 0; j < TCAND; ++j) {
        int r = 0;
#pragma unroll
        for (int o = 0; o < TCAND; ++o) {
            if (o != j)
                r += (simv[o] > simv[j] ||
                      (simv[o] == simv[j] && ka[o] < ka[j])) ? 1 : 0;
        }
        rk8[j] = r;
    }

    // ---- softmax over the 8 winners ----
    float mx = -1e30f;
#pragma unroll
    for (int j = 0; j < TCAND; ++j) if (rk8[j] < KTOP) mx = fmaxf(mx, lgv[j]);
    float e[TCAND]; float ps = 0.f;
#pragma unroll
    for (int j = 0; j < TCAND; ++j) {
        const float ee = (rk8[j] < KTOP) ? expf(lgv[j] - mx) : 0.f;
        e[j] = ee; ps += ee;
    }
    const float inv = 1.0f / ps;

    // ---- weighted V sum ----
    float oacc[12];
#pragma unroll
    for (int i = 0; i < 12; ++i) oacc[i] = 0.f;
#pragma unroll
    for (int j = 0; j < TCAND; ++j) {
        if (rk8[j] < KTOP) {
            const float p = e[j] * inv;
            const float* vp = Vmat + ((size_t)(b << 12) + ka[j]) * D_ + lane * 12;
#pragma unroll
            for (int i = 0; i < 3; ++i) {
                const float4 vv = *(const float4*)&vp[i * 4];
                oacc[i * 4 + 0] += p * vv.x; oacc[i * 4 + 1] += p * vv.y;
                oacc[i * 4 + 2] += p * vv.z; oacc[i * 4 + 3] += p * vv.w;
            }
        }
    }

#pragma unroll
    for (int i = 0; i < 3; ++i)
        *(float4*)&laccum[w][lane * 12 + i * 4] = *(float4*)&oacc[i * 4];
    __syncthreads();
    for (int d = tid; d < D_; d += 256) {
        const float s = laccum[0][d] + laccum[1][d] + laccum[2][d] + laccum[3][d];
        atomicAdd(&out[(size_t)b * D_ + d], s * (1.0f / N_));
    }
}

// ---------------------------------------------------------------------------
extern "C" void kernel_launch(void* const* d_in, const int* in_sizes, int n_in,
                              void* d_out, int out_size, void* d_ws, size_t ws_size,
                              hipStream_t stream)
{
    const float* feats = (const float*)d_in[0];
    const float* Wq    = (const float*)d_in[1];
    const float* bq    = (const float*)d_in[2];
    const float* Wkv   = (const float*)d_in[3];
    const float* bkv   = (const float*)d_in[4];
    float* out = (float*)d_out;

    // workspace layout (~248 MB)
    char* ws = (char*)d_ws;
    size_t off = 0;
    float*  Q    = (float*)(ws + off);  off += (size_t)M_ * D_ * sizeof(float);
    float*  Km   = (float*)(ws + off);  off += (size_t)M_ * D_ * sizeof(float);
    float*  Vm   = (float*)(ws + off);  off += (size_t)M_ * D_ * sizeof(float);
    ushort* qn   = (ushort*)(ws + off); off += (size_t)M_ * D_ * sizeof(ushort);
    ushort* kn   = (ushort*)(ws + off); off += (size_t)M_ * D_ * sizeof(ushort);
    float*  rqv  = (float*)(ws + off);  off += (size_t)M_ * sizeof(float);
    float*  rkv  = (float*)(ws + off);  off += (size_t)M_ * sizeof(float);
    ushort* S    = (ushort*)(ws + off); off += (size_t)N_ * N_ * sizeof(ushort);
    unsigned int* Part = (unsigned int*)(ws + off);
    off += (size_t)M_ * KSPLIT * TCAND * sizeof(unsigned int);
    (void)ws_size; (void)in_sizes; (void)n_in; (void)out_size;

    qkv_gemm<<<dim3(2304 / G1_BN, M_ / G1_BM), 256, 0, stream>>>(
        feats, Wq, bq, Wkv, bkv, Q, Km, Vm);
    norm_bf16<<<(2 * M_) / 4, 256, 0, stream>>>(Q, Km, qn, kn, rqv, rkv);

    for (int b = 0; b < B_; ++b) {
        sim_gemm<<<dim3(N_ / 128, N_ / 128), 256, 0, stream>>>(
            qn + (size_t)b * N_ * D_, kn + (size_t)b * N_ * D_, S);
        sel_topk<<<dim3(N_ / 256, KSPLIT), 256, 0, stream>>>(
            S, Part + (size_t)b * N_ * (KSPLIT * TCAND));
    }

    zero_out<<<(B_ * D_ + 255) / 256, 256, 0, stream>>>(out);
    merge_rescore_attn<<<M_ / 4, 256, 0, stream>>>(
        Q, Km, Vm, rqv, rkv, Part, out);
}

// Round 5
// 728.859 us; speedup vs baseline: 3.7949x; 1.6326x over previous
//
#include <hip/hip_runtime.h>
#include <hip/hip_bf16.h>
#include <math.h>

#define B_ 4
#define N_ 4096
#define D_ 768
#define KTOP 8
#define M_ (B_*N_)          // 16384
#define TCAND 12            // bf16 candidates kept per row (margin over KTOP=8)
#define KSPLIT 16           // k-range splits in select kernel (256 k each)

typedef __attribute__((ext_vector_type(8))) short short8;
typedef __attribute__((ext_vector_type(4))) float f32x4;
typedef _Float16 half_t;
typedef __attribute__((ext_vector_type(8))) _Float16 half8;
typedef __attribute__((ext_vector_type(4))) _Float16 half4;

__device__ __forceinline__ ushort f2bf(float f) {
    unsigned int u = __float_as_uint(f);
    unsigned int r = (u + 0x7FFFu + ((u >> 16) & 1u)) >> 16;
    return (ushort)r;
}

__device__ __forceinline__ void gload16(const void* g, void* l) {
    __builtin_amdgcn_global_load_lds(
        (const __attribute__((address_space(1))) unsigned int*)g,
        (__attribute__((address_space(3))) unsigned int*)l, 16, 0, 0);
}

// ---------------------------------------------------------------------------
// Kernel 1a: split feats into fp16 hi/lo (Dekker 2-way split).
// feats = Fh + Fl + r, |r| ~ 2^-24 |feats|.
// ---------------------------------------------------------------------------
__global__ __launch_bounds__(256) void split_feats(
    const float* __restrict__ f, half_t* __restrict__ Fh, half_t* __restrict__ Fl)
{
    const int i = (blockIdx.x * 256 + threadIdx.x) * 4;   // exact coverage
    const float4 v = *(const float4*)&f[i];
    float x[4] = {v.x, v.y, v.z, v.w};
    half4 h, l;
#pragma unroll
    for (int c = 0; c < 4; ++c) {
        const half_t hh = (half_t)x[c];
        h[c] = hh;
        l[c] = (half_t)(x[c] - (float)hh);
    }
    *(half4*)&Fh[i] = h;
    *(half4*)&Fl[i] = l;
}

// ---------------------------------------------------------------------------
// Kernel 1b: build W^T fp16 hi/lo splits, scaled by 2^12 (exact), for the
// combined [2304][768] B-operand: rows 0-767=Wq cols, 768-1535=K cols,
// 1536-2303=V cols. 64x64 LDS transpose tiles.
// ---------------------------------------------------------------------------
__global__ __launch_bounds__(256) void split_w(
    const float* __restrict__ Wq, const float* __restrict__ Wkv,
    half_t* __restrict__ Wth, half_t* __restrict__ Wtl)
{
    __shared__ float T[64][65];
    const int tid = threadIdx.x;
    const int n0 = blockIdx.x * 64;     // dest row block (output col)
    const int k0 = blockIdx.y * 64;     // dest col block (contraction)

    // read 64(k) x 64(n) source tile, coalesced over n
    const int nl = tid & 63;
#pragma unroll
    for (int r = 0; r < 16; ++r) {
        const int kl = (tid >> 6) * 16 + r;
        const int n  = n0 + nl;
        const float w = (n < 768)
            ? Wq[(size_t)(k0 + kl) * 768 + n]
            : Wkv[(size_t)(k0 + kl) * 1536 + (n - 768)];
        T[kl][nl] = w;
    }
    __syncthreads();

    // write transposed, coalesced over k, with x4096 scale + fp16 split
    const int kl2 = tid & 63;
#pragma unroll
    for (int r = 0; r < 16; ++r) {
        const int nl2 = (tid >> 6) * 16 + r;
        const float ws = T[kl2][nl2] * 4096.0f;
        const half_t h = (half_t)ws;
        const half_t l = (half_t)(ws - (float)h);
        Wth[(size_t)(n0 + nl2) * D_ + k0 + kl2] = h;
        Wtl[(size_t)(n0 + nl2) * D_ + k0 + kl2] = l;
    }
}

// ---------------------------------------------------------------------------
// Kernel 1c: QKV projection via fp16-split MFMA.
// C[m][n] = (Fh+Fl).(Wh+Wl)/4096 + bias, n<768 -> Q, <1536 -> K, else V.
// QK region: 3 terms (hh, hl, lh) -> fp32-grade exact (~4e-7 dot error).
// V region: 1 term (hh) -> ~2e-4 rel, harmless after p-weighted mean.
// 128x128 tile, BK=64, 4 waves, global_load_lds staging (m97 structure).
// ---------------------------------------------------------------------------
__global__ __launch_bounds__(256) void qkv_mfma(
    const half_t* __restrict__ Fh, const half_t* __restrict__ Fl,
    const half_t* __restrict__ Wth, const half_t* __restrict__ Wtl,
    const float* __restrict__ bq, const float* __restrict__ bkv,
    float* __restrict__ Q, float* __restrict__ Km, float* __restrict__ Vm)
{
    __shared__ __align__(16) half_t Ah[128 * 64];
    __shared__ __align__(16) half_t Al[128 * 64];
    __shared__ __align__(16) half_t Bh[128 * 64];
    __shared__ __align__(16) half_t Bl[128 * 64];

    const int tid  = threadIdx.x;
    const int lane = tid & 63, w = tid >> 6;
    const int wr = w >> 1, wc = w & 1;
    const int r16 = lane & 15, kq = lane >> 4;
    const int n0 = blockIdx.x * 128;
    const int m0 = blockIdx.y * 128;
    const bool three = (n0 < 1536);      // uniform per block

    const half_t* ah = Fh  + (size_t)(m0 + (tid >> 3)) * D_ + (tid & 7) * 8;
    const half_t* al = Fl  + (size_t)(m0 + (tid >> 3)) * D_ + (tid & 7) * 8;
    const half_t* bh = Wth + (size_t)(n0 + (tid >> 3)) * D_ + (tid & 7) * 8;
    const half_t* bl = Wtl + (size_t)(n0 + (tid >> 3)) * D_ + (tid & 7) * 8;
    half_t* lAh = Ah + (w << 9);   // wave-uniform base, lane x16B appended by HW
    half_t* lAl = Al + (w << 9);
    half_t* lBh = Bh + (w << 9);
    half_t* lBl = Bl + (w << 9);

    f32x4 acc[4][4];
#pragma unroll
    for (int mi = 0; mi < 4; ++mi)
#pragma unroll
        for (int ni = 0; ni < 4; ++ni) acc[mi][ni] = (f32x4)0.f;

    for (int kb = 0; kb < D_ / 64; ++kb) {
#pragma unroll
        for (int i = 0; i < 4; ++i) {
            gload16(ah + (size_t)i * 32 * D_ + kb * 64, lAh + i * 2048);
            gload16(bh + (size_t)i * 32 * D_ + kb * 64, lBh + i * 2048);
        }
        if (three) {
#pragma unroll
            for (int i = 0; i < 4; ++i) {
                gload16(al + (size_t)i * 32 * D_ + kb * 64, lAl + i * 2048);
                gload16(bl + (size_t)i * 32 * D_ + kb * 64, lBl + i * 2048);
            }
        }
        __syncthreads();
#pragma unroll
        for (int kk = 0; kk < 2; ++kk) {
            half8 fa[4], fal[4], fb[4], fbl[4];
#pragma unroll
            for (int mi = 0; mi < 4; ++mi) {
                const int ro = (wr * 64 + mi * 16 + r16) * 64 + kk * 32 + kq * 8;
                fa[mi]  = *(const half8*)&Ah[ro];
                fal[mi] = *(const half8*)&Al[ro];
            }
#pragma unroll
            for (int ni = 0; ni < 4; ++ni) {
                const int ro = (wc * 64 + ni * 16 + r16) * 64 + kk * 32 + kq * 8;
                fb[ni]  = *(const half8*)&Bh[ro];
                fbl[ni] = *(const half8*)&Bl[ro];
            }
#pragma unroll
            for (int mi = 0; mi < 4; ++mi)
#pragma unroll
                for (int ni = 0; ni < 4; ++ni) {
                    acc[mi][ni] = __builtin_amdgcn_mfma_f32_16x16x32_f16(
                        fa[mi], fb[ni], acc[mi][ni], 0, 0, 0);
                    if (three) {
                        acc[mi][ni] = __builtin_amdgcn_mfma_f32_16x16x32_f16(
                            fa[mi], fbl[ni], acc[mi][ni], 0, 0, 0);
                        acc[mi][ni] = __builtin_amdgcn_mfma_f32_16x16x32_f16(
                            fal[mi], fb[ni], acc[mi][ni], 0, 0, 0);
                    }
                }
        }
        __syncthreads();
    }

    const float unscale = 1.0f / 4096.0f;
#pragma unroll
    for (int ni = 0; ni < 4; ++ni) {
        const int n = n0 + wc * 64 + ni * 16 + r16;
        const float bias = (n0 < 768) ? bq[n] : bkv[n - 768];
        float* dst; int nn;
        if      (n0 < 768)  { dst = Q;  nn = n; }
        else if (n0 < 1536) { dst = Km; nn = n - 768; }
        else                { dst = Vm; nn = n - 1536; }
#pragma unroll
        for (int mi = 0; mi < 4; ++mi)
#pragma unroll
            for (int r = 0; r < 4; ++r) {
                const int m = m0 + wr * 64 + mi * 16 + kq * 4 + r;
                dst[(size_t)m * D_ + nn] = acc[mi][ni][r] * unscale + bias;
            }
    }
}

// ---------------------------------------------------------------------------
// Kernel 2: row L2 norms of Q,K + write normalized bf16 copies + 1/norm.
// One wave per row.
// ---------------------------------------------------------------------------
__global__ __launch_bounds__(256) void norm_bf16(
    const float* __restrict__ Q, const float* __restrict__ Km,
    ushort* __restrict__ qn, ushort* __restrict__ kn,
    float* __restrict__ rqinv, float* __restrict__ rkinv)
{
    const int wid  = blockIdx.x * 4 + (threadIdx.x >> 6);
    const int lane = threadIdx.x & 63;
    const float* src; ushort* dst; float* rv; int r;
    if (wid < M_) { src = Q;  dst = qn; rv = rqinv; r = wid; }
    else          { src = Km; dst = kn; rv = rkinv; r = wid - M_; }
    const float* p = src + (size_t)r * D_ + lane * 12;
    float v[12];
#pragma unroll
    for (int i = 0; i < 3; ++i) *(float4*)&v[i * 4] = *(const float4*)&p[i * 4];
    float s = 0.f;
#pragma unroll
    for (int i = 0; i < 12; ++i) s += v[i] * v[i];
#pragma unroll
    for (int off = 32; off; off >>= 1) s += __shfl_xor(s, off);
    const float rinv = 1.0f / fmaxf(sqrtf(s), 1e-12f);
    ushort* op = dst + (size_t)r * D_ + lane * 12;
#pragma unroll
    for (int i = 0; i < 3; ++i) {
        ushort4 o;
        o.x = f2bf(v[i * 4 + 0] * rinv); o.y = f2bf(v[i * 4 + 1] * rinv);
        o.z = f2bf(v[i * 4 + 2] * rinv); o.w = f2bf(v[i * 4 + 3] * rinv);
        *(ushort4*)&op[i * 4] = o;
    }
    if (lane == 0) rv[r] = rinv;
}

// ---------------------------------------------------------------------------
// Kernel 3: bf16 MFMA sim GEMM (one batch): S[q][k] = qn . kn^T, bf16 out,
// diagonal forced to bf16 lowest. 128x128 tile, BK=64, 4 waves.
// ---------------------------------------------------------------------------
__global__ __launch_bounds__(256) void sim_gemm(
    const ushort* __restrict__ qn, const ushort* __restrict__ kn,
    ushort* __restrict__ S)
{
    __shared__ __align__(16) ushort As[128 * 64];
    __shared__ __align__(16) ushort Bs[128 * 64];

    const int tid  = threadIdx.x;
    const int lane = tid & 63, w = tid >> 6;
    const int wr = w >> 1, wc = w & 1;
    const int r16 = lane & 15, kq = lane >> 4;
    const int k0 = blockIdx.x * 128;
    const int q0 = blockIdx.y * 128;

    const ushort* qsrc = qn + (size_t)(q0 + (tid >> 3)) * D_ + (tid & 7) * 8;
    const ushort* ksrc = kn + (size_t)(k0 + (tid >> 3)) * D_ + (tid & 7) * 8;
    ushort* lA = As + ((tid >> 6) << 9);
    ushort* lB = Bs + ((tid >> 6) << 9);

    f32x4 acc[4][4];
#pragma unroll
    for (int mi = 0; mi < 4; ++mi)
#pragma unroll
        for (int ni = 0; ni < 4; ++ni) acc[mi][ni] = (f32x4)0.f;

    for (int kb = 0; kb < D_ / 64; ++kb) {
#pragma unroll
        for (int i = 0; i < 4; ++i) {
            gload16(qsrc + (size_t)i * 32 * D_ + kb * 64, lA + i * 2048);
            gload16(ksrc + (size_t)i * 32 * D_ + kb * 64, lB + i * 2048);
        }
        __syncthreads();
#pragma unroll
        for (int kk = 0; kk < 2; ++kk) {
            short8 a[4], bfr[4];
#pragma unroll
            for (int mi = 0; mi < 4; ++mi)
                a[mi] = *(const short8*)&As[(wr * 64 + mi * 16 + r16) * 64 + kk * 32 + kq * 8];
#pragma unroll
            for (int ni = 0; ni < 4; ++ni)
                bfr[ni] = *(const short8*)&Bs[(wc * 64 + ni * 16 + r16) * 64 + kk * 32 + kq * 8];
#pragma unroll
            for (int mi = 0; mi < 4; ++mi)
#pragma unroll
                for (int ni = 0; ni < 4; ++ni)
                    acc[mi][ni] = __builtin_amdgcn_mfma_f32_16x16x32_bf16(
                        a[mi], bfr[ni], acc[mi][ni], 0, 0, 0);
        }
        __syncthreads();
    }

#pragma unroll
    for (int mi = 0; mi < 4; ++mi)
#pragma unroll
        for (int ni = 0; ni < 4; ++ni)
#pragma unroll
            for (int r = 0; r < 4; ++r) {
                const int qq = q0 + wr * 64 + mi * 16 + kq * 4 + r;
                const int kk = k0 + wc * 64 + ni * 16 + r16;
                const float val = acc[mi][ni][r];
                const ushort bv = (qq == kk) ? (ushort)0xFF7Fu : f2bf(val);
                S[(size_t)qq * N_ + kk] = bv;
            }
}

// ---------------------------------------------------------------------------
// Kernel 4: branchless packed top-12 per (row, 256-wide k split).
// ---------------------------------------------------------------------------
__global__ __launch_bounds__(256) void sel_topk(
    const ushort* __restrict__ S, unsigned int* __restrict__ Part)
{
    const int tid = threadIdx.x;
    const int row = blockIdx.x * 256 + tid;
    const int ks  = blockIdx.y;
    const int kbase = ks * 256;
    const int KREV  = (N_ - 1) - kbase;

    const ushort* sp = S + (size_t)row * N_ + kbase;
    unsigned int t[TCAND];
#pragma unroll
    for (int i = 0; i < TCAND; ++i) t[i] = 0u;

    for (int j = 0; j < 256; j += 8) {
        const uint4 dv = *(const uint4*)(sp + j);
        unsigned int dw[4];
        dw[0] = dv.x; dw[1] = dv.y; dw[2] = dv.z; dw[3] = dv.w;
#pragma unroll
        for (int q = 0; q < 4; ++q) {
            const unsigned int vlo = dw[q] & 0xFFFFu;
            const unsigned int vhi = dw[q] >> 16;
            const unsigned int plo =
                ((vlo ^ (0x8000u + ((vlo >> 15) * 0x7FFFu))) << 16) |
                (unsigned int)(KREV - (j + 2 * q));
            const unsigned int phi =
                ((vhi ^ (0x8000u + ((vhi >> 15) * 0x7FFFu))) << 16) |
                (unsigned int)(KREV - (j + 2 * q + 1));
            unsigned int p = plo;
#pragma unroll
            for (int i = 0; i < TCAND; ++i) {
                const unsigned int mx = max(t[i], p);
                const unsigned int mn = min(t[i], p);
                t[i] = mx; p = mn;
            }
            p = phi;
#pragma unroll
            for (int i = 0; i < TCAND; ++i) {
                const unsigned int mx = max(t[i], p);
                const unsigned int mn = min(t[i], p);
                t[i] = mx; p = mn;
            }
        }
    }

    unsigned int* op = Part + (size_t)row * (KSPLIT * TCAND) + ks * TCAND;
#pragma unroll
    for (int i = 0; i < TCAND; ++i) op[i] = t[i];
}

// ---------------------------------------------------------------------------
// Kernel 5: zero output
// ---------------------------------------------------------------------------
__global__ void zero_out(float* __restrict__ out)
{
    const int i = blockIdx.x * 256 + threadIdx.x;
    if (i < B_ * D_) out[i] = 0.f;
}

// ---------------------------------------------------------------------------
// Kernel 6: merge 192 partials -> bf16 top-12 -> fp32 rescore -> exact top-8
// -> softmax -> V gather -> batch mean. One wave per row.
// ---------------------------------------------------------------------------
__global__ __launch_bounds__(256) void merge_rescore_attn(
    const float* __restrict__ Q, const float* __restrict__ Kmat,
    const float* __restrict__ Vmat, const float* __restrict__ rqinv,
    const float* __restrict__ rkinv, const unsigned int* __restrict__ Part,
    float* __restrict__ out)
{
    __shared__ float laccum[4][D_];
    const int tid  = threadIdx.x;
    const int w    = tid >> 6, lane = tid & 63;
    const int row  = blockIdx.x * 4 + w;
    const int b    = row >> 12;

    const unsigned int* pp = Part + (size_t)row * (KSPLIT * TCAND);
    unsigned int c0 = pp[lane], c1 = pp[64 + lane], c2 = pp[128 + lane];
    unsigned int mysel = 0u;
#pragma unroll
    for (int it = 0; it < TCAND; ++it) {
        unsigned int m = max(c0, max(c1, c2));
#pragma unroll
        for (int off = 32; off; off >>= 1) m = max(m, __shfl_xor(m, off));
        c0 = (c0 == m) ? 0u : c0;
        c1 = (c1 == m) ? 0u : c1;
        c2 = (c2 == m) ? 0u : c2;
        mysel = (lane == it) ? m : mysel;
    }
    const int kj_lane = (N_ - 1) - (int)(mysel & 0xFFFFu);

    float qv[12];
    {
        const float* qp = Q + (size_t)row * D_ + lane * 12;
#pragma unroll
        for (int i = 0; i < 3; ++i) *(float4*)&qv[i * 4] = *(const float4*)&qp[i * 4];
    }
    const float rq = rqinv[row];
    const float scale = 0.03608439182435161f;   // 1/sqrt(768)

    float simv[TCAND], lgv[TCAND];
    int   ka[TCAND];
#pragma unroll
    for (int j = 0; j < TCAND; ++j) {
        const int kj = __shfl(kj_lane, j);
        ka[j] = kj;
        const float* kp = Kmat + ((size_t)(b << 12) + kj) * D_ + lane * 12;
        float d = 0.f;
#pragma unroll
        for (int i = 0; i < 3; ++i) {
            const float4 kv = *(const float4*)&kp[i * 4];
            d += qv[i * 4 + 0] * kv.x + qv[i * 4 + 1] * kv.y +
                 qv[i * 4 + 2] * kv.z + qv[i * 4 + 3] * kv.w;
        }
#pragma unroll
        for (int off = 32; off; off >>= 1) d += __shfl_xor(d, off);
        simv[j] = d * rq * rkinv[(b << 12) + kj];
        lgv[j]  = d * scale;
    }

    int rk8[TCAND];
#pragma unroll
    for (int j = 0; j < TCAND; ++j) {
        int r = 0;
#pragma unroll
        for (int o = 0; o < TCAND; ++o) {
            if (o != j)
                r += (simv[o] > simv[j] ||
                      (simv[o] == simv[j] && ka[o] < ka[j])) ? 1 : 0;
        }
        rk8[j] = r;
    }

    float mx = -1e30f;
#pragma unroll
    for (int j = 0; j < TCAND; ++j) if (rk8[j] < KTOP) mx = fmaxf(mx, lgv[j]);
    float e[TCAND]; float ps = 0.f;
#pragma unroll
    for (int j = 0; j < TCAND; ++j) {
        const float ee = (rk8[j] < KTOP) ? expf(lgv[j] - mx) : 0.f;
        e[j] = ee; ps += ee;
    }
    const float inv = 1.0f / ps;

    float oacc[12];
#pragma unroll
    for (int i = 0; i < 12; ++i) oacc[i] = 0.f;
#pragma unroll
    for (int j = 0; j < TCAND; ++j) {
        if (rk8[j] < KTOP) {
            const float p = e[j] * inv;
            const float* vp = Vmat + ((size_t)(b << 12) + ka[j]) * D_ + lane * 12;
#pragma unroll
            for (int i = 0; i < 3; ++i) {
                const float4 vv = *(const float4*)&vp[i * 4];
                oacc[i * 4 + 0] += p * vv.x; oacc[i * 4 + 1] += p * vv.y;
                oacc[i * 4 + 2] += p * vv.z; oacc[i * 4 + 3] += p * vv.w;
            }
        }
    }

#pragma unroll
    for (int i = 0; i < 3; ++i)
        *(float4*)&laccum[w][lane * 12 + i * 4] = *(float4*)&oacc[i * 4];
    __syncthreads();
    for (int d = tid; d < D_; d += 256) {
        const float s = laccum[0][d] + laccum[1][d] + laccum[2][d] + laccum[3][d];
        atomicAdd(&out[(size_t)b * D_ + d], s * (1.0f / N_));
    }
}

// ---------------------------------------------------------------------------
extern "C" void kernel_launch(void* const* d_in, const int* in_sizes, int n_in,
                              void* d_out, int out_size, void* d_ws, size_t ws_size,
                              hipStream_t stream)
{
    const float* feats = (const float*)d_in[0];
    const float* Wq    = (const float*)d_in[1];
    const float* bq    = (const float*)d_in[2];
    const float* Wkv   = (const float*)d_in[3];
    const float* bkv   = (const float*)d_in[4];
    float* out = (float*)d_out;

    // workspace layout (~243 MB); Fh/Fl alias qn/kn (disjoint liveness:
    // Fh/Fl dead after qkv_mfma, qn/kn written by norm_bf16 afterwards).
    char* ws = (char*)d_ws;
    size_t off = 0;
    float*  Q    = (float*)(ws + off);  off += (size_t)M_ * D_ * sizeof(float);
    float*  Km   = (float*)(ws + off);  off += (size_t)M_ * D_ * sizeof(float);
    float*  Vm   = (float*)(ws + off);  off += (size_t)M_ * D_ * sizeof(float);
    char*   unio = ws + off;            off += 2 * (size_t)M_ * D_ * sizeof(ushort);
    half_t* Fh   = (half_t*)unio;
    half_t* Fl   = (half_t*)(unio + (size_t)M_ * D_ * sizeof(half_t));
    ushort* qn   = (ushort*)unio;
    ushort* kn   = (ushort*)(unio + (size_t)M_ * D_ * sizeof(ushort));
    float*  rqv  = (float*)(ws + off);  off += (size_t)M_ * sizeof(float);
    float*  rkv  = (float*)(ws + off);  off += (size_t)M_ * sizeof(float);
    half_t* Wth  = (half_t*)(ws + off); off += (size_t)2304 * D_ * sizeof(half_t);
    half_t* Wtl  = (half_t*)(ws + off); off += (size_t)2304 * D_ * sizeof(half_t);
    ushort* S    = (ushort*)(ws + off); off += (size_t)N_ * N_ * sizeof(ushort);
    unsigned int* Part = (unsigned int*)(ws + off);
    off += (size_t)M_ * KSPLIT * TCAND * sizeof(unsigned int);
    (void)ws_size; (void)in_sizes; (void)n_in; (void)out_size;

    split_feats<<<(M_ * D_) / 1024, 256, 0, stream>>>(feats, Fh, Fl);
    split_w<<<dim3(2304 / 64, D_ / 64), 256, 0, stream>>>(Wq, Wkv, Wth, Wtl);
    qkv_mfma<<<dim3(2304 / 128, M_ / 128), 256, 0, stream>>>(
        Fh, Fl, Wth, Wtl, bq, bkv, Q, Km, Vm);
    norm_bf16<<<(2 * M_) / 4, 256, 0, stream>>>(Q, Km, qn, kn, rqv, rkv);

    for (int b = 0; b < B_; ++b) {
        sim_gemm<<<dim3(N_ / 128, N_ / 128), 256, 0, stream>>>(
            qn + (size_t)b * N_ * D_, kn + (size_t)b * N_ * D_, S);
        sel_topk<<<dim3(N_ / 256, KSPLIT), 256, 0, stream>>>(
            S, Part + (size_t)b * N_ * (KSPLIT * TCAND));
    }

    zero_out<<<(B_ * D_ + 255) / 256, 256, 0, stream>>>(out);
    merge_rescore_attn<<<M_ / 4, 256, 0, stream>>>(
        Q, Km, Vm, rqv, rkv, Part, out);
}